// Round 8
// baseline (241.730 us; speedup 1.0000x reference)
//
#include <hip/hip_runtime.h>
#include <hip/hip_bf16.h>

#define SEQ   2048
#define EMB   1024
#define NHEAD 16
#define DHEAD 64
#define BATCH 2
#define MTOT  (BATCH*SEQ)   // 4096
#define QT    128           // queries per attention block
#define KT    64            // keys per tile
#define NTILE (SEQ/KT)      // 32

typedef __attribute__((ext_vector_type(8))) short s8v;   // 8 bf16 (4 VGPRs)
typedef __attribute__((ext_vector_type(4))) short s4v;   // 4 bf16 (8 B)
typedef __attribute__((ext_vector_type(4))) float f4v;   // mfma accum

__device__ __forceinline__ short f2b(float f) {
    union { float fl; unsigned u; } v; v.fl = f;
    unsigned u = v.u;
    u = (u + 0x7fffu + ((u >> 16) & 1u)) >> 16;   // round-to-nearest-even
    return (short)u;
}
// packed fp32x2 -> bf16x2 (v_cvt_pk_bf16_f32); rounded values also feed the
// softmax denominator (consistency => rounding-mode-agnostic).
__device__ __forceinline__ unsigned pk2(float a, float b) {
    union { __hip_bfloat162 h; unsigned u; } c;
    c.h = __float22bfloat162_rn(float2{a, b});
    return c.u;
}

#if __has_builtin(__builtin_amdgcn_exp2f)
__device__ __forceinline__ float exp2_fast(float x) { return __builtin_amdgcn_exp2f(x); }
#else
__device__ __forceinline__ float exp2_fast(float x) { return exp2f(x); }
#endif

// gfx950 cross-lane half-swaps: dst upper part <-> src lower part.
__device__ __forceinline__ void pl32swap(unsigned &a, unsigned &b) {
    asm("v_permlane32_swap_b32 %0, %1" : "+v"(a), "+v"(b));
}
__device__ __forceinline__ void pl16swap(unsigned &a, unsigned &b) {
    asm("v_permlane16_swap_b32 %0, %1" : "+v"(a), "+v"(b));
}

// Raw workgroup barrier: LDS-visibility only (lgkmcnt drain), does NOT drain
// vmcnt — outstanding global prefetch loads stay in flight across it.
__device__ __forceinline__ void bar_lds() {
    asm volatile("s_waitcnt lgkmcnt(0)\n\ts_barrier" ::: "memory");
}

// async global->LDS DMA, 16 B/lane; LDS dest = wave-uniform base + lane*16.
__device__ __forceinline__ void gl_lds16(const short* g, short* l) {
    __builtin_amdgcn_global_load_lds(
        (const __attribute__((address_space(1))) void*)g,
        (__attribute__((address_space(3))) void*)l, 16, 0, 0);
}

// ---- fp32 -> bf16 convert + chunk swizzle ----
// Output rows are 1024 bf16 = 16 aligned 128B groups of 8 16B-chunks.
// Chunk c of row r is stored at slot (c&~7) | ((c&7) ^ (r&7)) so that
// global_load_lds' contiguous DMA lands a bank-uniform LDS image.
__global__ __launch_bounds__(256)
void cvt_swz(const float* __restrict__ s0, const float* __restrict__ s1,
             const float* __restrict__ s2, const float* __restrict__ s3,
             const float* __restrict__ s4,
             short* __restrict__ d0, short* __restrict__ d1,
             short* __restrict__ d2, short* __restrict__ d3,
             short* __restrict__ d4)
{
    const int seg = blockIdx.y;
    const float* s = seg == 0 ? s0 : seg == 1 ? s1 : seg == 2 ? s2 : seg == 3 ? s3 : s4;
    short*       d = seg == 0 ? d0 : seg == 1 ? d1 : seg == 2 ? d2 : seg == 3 ? d3 : d4;
    const int nchunk = (seg == 0 ? MTOT * EMB : EMB * EMB) / 8;   // 16B chunks
    const int stride = gridDim.x * 256;
    for (int i = blockIdx.x * 256 + threadIdx.x; i < nchunk; i += stride) {
        const int row = i >> 7;         // 128 chunks per 1024-col row
        const int c   = i & 127;
        const float4 v0 = *(const float4*)(s + (size_t)i * 8);
        const float4 v1 = *(const float4*)(s + (size_t)i * 8 + 4);
        s8v o;
        o[0] = f2b(v0.x); o[1] = f2b(v0.y); o[2] = f2b(v0.z); o[3] = f2b(v0.w);
        o[4] = f2b(v1.x); o[5] = f2b(v1.y); o[6] = f2b(v1.z); o[7] = f2b(v1.w);
        const int cp = (c & ~7) | ((c & 7) ^ (row & 7));
        *(s8v*)(d + (size_t)row * EMB + cp * 8) = o;
    }
}

// NT GEMM via global_load_lds (m97 structure): C = A*W^T + bias.
// A, W are bf16 with swizzled 16B chunks (see cvt_swz). LDS rows unpadded
// (128 B); frag reads address slot (kk*4+quad)^(l16&7) -> bank-uniform.
// FUSED3: 3 matrices (QKV); mat 2 writes V transposed per-head [b][h][d][s].
// mat 0 (Q) output is prescaled by 0.125*log2(e) so attention uses exp2.
//
// r8: for all outputs EXCEPT the V matrix, the MFMA operands are SWAPPED
// (acc = mfma(wf, af)): D's col becomes the TOKEN dim and row the N dim,
// so each thread holds 4 CONSECUTIVE n for one token -> the C-write is one
// s4v (bf16) / float4 (fp32) vector store instead of 4 scalar stores, and
// the bias is one float4 load. 64 scalar stores/thread -> 16 vector stores.
// Fragment addressing is unchanged (A/B lane maps are identical shapes).
// V (mat 2) keeps the original order: its store is s4v along tokens already.
template<int NT, bool FUSED3>
__global__ __launch_bounds__(256, 3)
void gemm_bb3(const short* __restrict__ A,
              const short* __restrict__ W0, const short* __restrict__ W1, const short* __restrict__ W2,
              const float* __restrict__ B0, const float* __restrict__ B1, const float* __restrict__ B2,
              void* __restrict__ C0, void* __restrict__ C1, void* __restrict__ C2)
{
    constexpr int JN = NT / 32;
    const int K = EMB, N = EMB;
    const int ntiles = EMB / NT;
    const int mat = blockIdx.x / ntiles;
    const int n0  = (blockIdx.x % ntiles) * NT;
    const int m0  = blockIdx.y * 128;
    const short* W  = (mat == 0) ? W0 : (mat == 1 ? W1 : W2);
    const float* Bi = (mat == 0) ? B0 : (mat == 1 ? B1 : B2);
    void*        C  = (mat == 0) ? C0 : (mat == 1 ? C1 : C2);
    const float qscale = (FUSED3 && mat == 0) ? 0.18033688f : 1.0f;  // 1/8*log2e

    __shared__ __align__(16) short As[128 * 64];
    __shared__ __align__(16) short Ws[NT * 64];

    const int tid  = threadIdx.x;
    const int lane = tid & 63;
    const int wave = tid >> 6;
    const int quad = lane >> 4;
    const int l16  = lane & 15;
    const int l8   = l16 & 7;
    const int wm   = wave >> 1;
    const int wn   = wave & 1;

    f4v acc[4][JN] = {};

    const int srow = lane >> 3;    // staging row within 8-row group
    const int scol = (lane & 7) * 8;

    const bool vpath = FUSED3 && (mat == 2);   // uniform per block

    for (int k0 = 0; k0 < K; k0 += 64) {
        // ---- async DMA staging: A rows wave*32.., W rows wave*(NT/4).. ----
        #pragma unroll
        for (int p = 0; p < 4; ++p) {
            const int rbase = wave * 32 + p * 8;
            gl_lds16(A + (size_t)(m0 + rbase + srow) * K + k0 + scol,
                     As + rbase * 64);
        }
        #pragma unroll
        for (int p = 0; p < NT / 32; ++p) {
            const int rbase = wave * (NT / 4) + p * 8;
            gl_lds16(W + (size_t)(n0 + rbase + srow) * K + k0 + scol,
                     Ws + rbase * 64);
        }
        __syncthreads();   // drains the DMA (vmcnt) + barrier

        #pragma unroll
        for (int kk = 0; kk < 2; ++kk) {
            const int slot = ((kk * 4 + quad) ^ l8) * 8;
            s8v af[4], wf[JN];
            #pragma unroll
            for (int i = 0; i < 4; ++i)
                af[i] = *(const s8v*)(As + (wm * 64 + i * 16 + l16) * 64 + slot);
            #pragma unroll
            for (int j = 0; j < JN; ++j)
                wf[j] = *(const s8v*)(Ws + (wn * (NT / 2) + j * 16 + l16) * 64 + slot);
            if (!vpath) {
                // swapped: D[n][token] — col=token(l16), row=n(quad*4+reg)
                #pragma unroll
                for (int i = 0; i < 4; ++i)
                    #pragma unroll
                    for (int j = 0; j < JN; ++j)
                        acc[i][j] = __builtin_amdgcn_mfma_f32_16x16x32_bf16(
                            wf[j], af[i], acc[i][j], 0, 0, 0);
            } else {
                #pragma unroll
                for (int i = 0; i < 4; ++i)
                    #pragma unroll
                    for (int j = 0; j < JN; ++j)
                        acc[i][j] = __builtin_amdgcn_mfma_f32_16x16x32_bf16(
                            af[i], wf[j], acc[i][j], 0, 0, 0);
            }
        }
        __syncthreads();   // all waves done reading before next overwrite
    }

    if (!vpath) {
        // ---- swapped epilogue: thread holds n..n+3 for one token ----
        #pragma unroll
        for (int j = 0; j < JN; ++j) {
            const int nb = n0 + wn * (NT / 2) + j * 16 + quad * 4;
            const float4 bv = *(const float4*)(Bi + nb);
            #pragma unroll
            for (int i = 0; i < 4; ++i) {
                const int tok = m0 + wm * 64 + i * 16 + l16;
                if (FUSED3) {
                    union { unsigned uu[2]; s4v s; } ov;
                    ov.uu[0] = pk2((acc[i][j][0] + bv.x) * qscale,
                                   (acc[i][j][1] + bv.y) * qscale);
                    ov.uu[1] = pk2((acc[i][j][2] + bv.z) * qscale,
                                   (acc[i][j][3] + bv.w) * qscale);
                    *(s4v*)((short*)C + (size_t)tok * N + nb) = ov.s;
                } else {
                    float4 o4 = { acc[i][j][0] + bv.x, acc[i][j][1] + bv.y,
                                  acc[i][j][2] + bv.z, acc[i][j][3] + bv.w };
                    *(float4*)((float*)C + (size_t)tok * N + nb) = o4;
                }
            }
        }
    } else {
        // ---- V path (original): C/D col = lane&15 (n), row = quad*4+reg ----
        #pragma unroll
        for (int j = 0; j < JN; ++j) {
            const int n = n0 + wn * (NT / 2) + j * 16 + l16;
            const float bv = Bi[n];
            #pragma unroll
            for (int i = 0; i < 4; ++i) {
                const int mb = m0 + wm * 64 + i * 16 + quad * 4;
                const int bb = mb >> 11, s = mb & 2047;
                s4v ov;
                #pragma unroll
                for (int rr = 0; rr < 4; ++rr) ov[rr] = f2b(acc[i][j][rr] + bv);
                *(s4v*)((short*)C + ((size_t)(bb * 1024 + n)) * SEQ + s) = ov;
            }
        }
    }
}

// MFMA flash attention v7 (proven best: 49.4 us, R3). QT=128, 512 threads
// (8 waves x 16 q-rows), grid 512 = 2 blocks/CU. K/V staged by
// global_load_lds DMA with pre-swizzled per-lane global source addresses;
// waves 0-3 stage K, 4-7 stage V. P all-to-all via permlane; denominator
// via ones-MFMA; XCD head-affinity swizzle; exp2 with prescaled Q.
__global__ __launch_bounds__(512, 4)
void attn_mfma7(const short* Q, const short* __restrict__ Kg,
                const short* __restrict__ Vt, short* O)
{
    // dispatch i -> XCD i&7 (round-robin). Give each XCD 4 (b,h) combos.
    const int i    = blockIdx.x;          // 512 blocks
    const int xcd  = i & 7;
    const int slot = i >> 3;              // 0..63
    const int combo = xcd * 4 + (slot >> 4);   // (b,h) 0..31
    const int qb = slot & 15;                  // 16 q-blocks per (b,h)
    const int h  = combo & 15;
    const int b  = combo >> 4;
    const int q0 = qb * QT;

    const int tid  = threadIdx.x;
    const int lane = tid & 63;
    const int wave = tid >> 6;            // 0..7
    const int quad = lane >> 4;
    const int l16  = lane & 15;
    const int l8   = l16 & 7;

    __shared__ __align__(16) short Ks[2][64 * 64];   // [key][d]   swizzled image
    __shared__ __align__(16) short Vs[2][64 * 64];   // [d][key]   swizzled image

    // Q B-frags (prescaled by 0.125*log2e): wave handles 16 q-rows
    s8v qf[2];
    #pragma unroll
    for (int kk = 0; kk < 2; ++kk)
        qf[kk] = *(const s8v*)(Q + (size_t)(b * SEQ + q0 + wave * 16 + l16) * EMB
                                 + h * DHEAD + kk * 32 + quad * 8);

    f4v oacc[4] = {};   // [j: d-block] -> O^T[d][q]
    f4v sacc    = {};   // ones-MFMA row sums (col = q, all rows equal)
    s8v onef;
    #pragma unroll
    for (int e = 0; e < 8; ++e) onef[e] = (short)0x3F80;   // bf16 1.0

    // ---- DMA staging setup: lane (r,c) covers row r, physical chunk c ----
    const int r = lane >> 3, c = lane & 7;
    const int sc8 = (c ^ r) * 8;               // pre-swizzled source chunk
    const bool isK = wave < 4;
    const int wrow = (wave & 3) * 16;          // 16 rows per stager wave
    const size_t kbase = (size_t)(b * SEQ) * EMB + h * DHEAD;
    const size_t vbase = (size_t)((b * NHEAD + h) * DHEAD) * SEQ;
    // per-lane global source for tile 0
    const short* gsrc = isK ? Kg + kbase + (size_t)(wrow + r) * EMB + sc8
                            : Vt + vbase + (size_t)(wrow + r) * SEQ + sc8;
    const size_t gstep8 = isK ? (size_t)8 * EMB : (size_t)8 * SEQ;  // +8 rows
    const size_t tstep  = isK ? (size_t)KT * EMB : (size_t)KT;      // +1 tile
    short* const lbase  = (isK ? (short*)Ks : (short*)Vs) + wrow * 64;

    // prologue: issue DMA for tile 0 into buf 0
    gl_lds16(gsrc,          lbase);
    gl_lds16(gsrc + gstep8, lbase + 8 * 64);
    const short* gnext = gsrc + tstep;

    for (int t = 0; t < NTILE; ++t) {
        const int buf = t & 1;
        __syncthreads();   // vmcnt(0)+barrier: tile t landed everywhere;
                           // compute(t-1) done everywhere -> buf^1 is free
        if (t + 1 < NTILE) {
            short* ldst = lbase + (buf ^ 1) * (64 * 64);
            gl_lds16(gnext,          ldst);
            gl_lds16(gnext + gstep8, ldst + 8 * 64);
            gnext += tstep;
        }
        const short* KsB = Ks[buf];
        const short* VsB = Vs[buf];

        // ---- S^T[key][q] = K · Q^T (already in log2 domain) ----
        f4v sc[4] = {};
        #pragma unroll
        for (int kk = 0; kk < 2; ++kk) {
            const int ko = ((kk * 4 + quad) ^ l8) * 8;
            s8v kf[4];
            #pragma unroll
            for (int j = 0; j < 4; ++j)
                kf[j] = *(const s8v*)(KsB + (j * 16 + l16) * 64 + ko);
            #pragma unroll
            for (int j = 0; j < 4; ++j)
                sc[j] = __builtin_amdgcn_mfma_f32_16x16x32_bf16(
                    kf[j], qf[kk], sc[j], 0, 0, 0);
        }

        // ---- p = 2^s, pack to bf16 pairs ----
        unsigned u[4][2];
        #pragma unroll
        for (int j = 0; j < 4; ++j) {
            u[j][0] = pk2(exp2_fast(sc[j][0]), exp2_fast(sc[j][1]));
            u[j][1] = pk2(exp2_fast(sc[j][2]), exp2_fast(sc[j][3]));
        }

        // ---- in-register all-to-all over lane bits 4/5 ----
        #pragma unroll
        for (int r2 = 0; r2 < 2; ++r2) {
            pl32swap(u[0][r2], u[1][r2]);   // stage A: b5' = j&1
            pl32swap(u[2][r2], u[3][r2]);
            pl16swap(u[0][r2], u[1][r2]);   // stage B: b4' = orig b5
            pl16swap(u[2][r2], u[3][r2]);
        }
        union { unsigned uu[4]; s8v s; } pfa, pfb;
        pfa.uu[0] = u[0][0]; pfa.uu[1] = u[0][1]; pfa.uu[2] = u[1][0]; pfa.uu[3] = u[1][1];
        pfb.uu[0] = u[2][0]; pfb.uu[1] = u[2][1]; pfb.uu[2] = u[3][0]; pfb.uu[3] = u[3][1];

        // ---- O^T[d][q] += V^T[d][key] · P^T ; row sums via ones-MFMA ----
        #pragma unroll
        for (int kk = 0; kk < 2; ++kk) {
            const s8v pf = kk ? pfb.s : pfa.s;
            sacc = __builtin_amdgcn_mfma_f32_16x16x32_bf16(onef, pf, sacc, 0, 0, 0);
            const int ko = ((kk * 4 + quad) ^ l8) * 8;
            #pragma unroll
            for (int j = 0; j < 4; ++j) {
                const s8v vf = *(const s8v*)(VsB + (j * 16 + l16) * 64 + ko);
                oacc[j] = __builtin_amdgcn_mfma_f32_16x16x32_bf16(
                    vf, pf, oacc[j], 0, 0, 0);
            }
        }
    }

    // ---- denominator: every row of sacc holds the full sum for col q ----
    const float inv = 1.0f / sacc[0];

    __syncthreads();   // everyone done with K/V LDS; reuse all of Ks as Os
    short* Os = (short*)Ks;   // 128 rows x 64 shorts = 16 KB
    #pragma unroll
    for (int j = 0; j < 4; ++j) {
        union { unsigned uu[2]; s4v s; } ov;
        ov.uu[0] = pk2(oacc[j][0] * inv, oacc[j][1] * inv);
        ov.uu[1] = pk2(oacc[j][2] * inv, oacc[j][3] * inv);
        const int pc = ((j * 2 + (quad >> 1)) ^ l8) * 8 + (quad & 1) * 4;
        *(s4v*)(Os + (wave * 16 + l16) * 64 + pc) = ov.s;
    }
    bar_lds();

    // ---- coalesced store: LDS swizzle cancels the output chunk swizzle ----
    const int row = tid >> 2;            // 0..127
    const int cb  = (tid & 3) * 2;       // two physical chunks per thread
    #pragma unroll
    for (int c4 = 0; c4 < 2; ++c4) {
        const int pcc = cb + c4;
        const s8v tt = *(const s8v*)(Os + row * 64 + pcc * 8);
        *(s8v*)(O + (size_t)(b * SEQ + q0 + row) * EMB + h * DHEAD + pcc * 8) = tt;
    }
}

extern "C" void kernel_launch(void* const* d_in, const int* in_sizes, int n_in,
                              void* d_out, int out_size, void* d_ws, size_t ws_size,
                              hipStream_t stream)
{
    const float* x  = (const float*)d_in[0];
    const float* Wq = (const float*)d_in[1];
    const float* bq = (const float*)d_in[2];
    const float* Wk = (const float*)d_in[3];
    const float* bk = (const float*)d_in[4];
    const float* Wv = (const float*)d_in[5];
    const float* bv = (const float*)d_in[6];
    const float* Wo = (const float*)d_in[7];
    const float* bo = (const float*)d_in[8];
    float* out = (float*)d_out;   // fp32 output

    short* xb  = (short*)d_ws;                       // 4096x1024 bf16, swizzled
    short* Wqb = xb  + (size_t)MTOT * EMB;           // swizzled
    short* Wkb = Wqb + (size_t)EMB * EMB;
    short* Wvb = Wkb + (size_t)EMB * EMB;
    short* Wob = Wvb + (size_t)EMB * EMB;
    short* Qw  = Wob + (size_t)EMB * EMB;            // [token][1024] (Q: plain;
                                                     //  then O: swizzled)
    short* Kw  = Qw  + (size_t)MTOT * EMB;           // [token][1024] plain
    short* Vtw = Kw  + (size_t)MTOT * EMB;           // [b][h][d][s] plain

    cvt_swz<<<dim3(512, 5), 256, 0, stream>>>(x, Wq, Wk, Wv, Wo,
                                              xb, Wqb, Wkb, Wvb, Wob);

    gemm_bb3<128, true><<<dim3(24, 32), 256, 0, stream>>>(
        xb, Wqb, Wkb, Wvb, bq, bk, bv, Qw, Kw, Vtw);

    attn_mfma7<<<dim3(BATCH * NHEAD * (SEQ / QT)), 512, 0, stream>>>(Qw, Kw, Vtw, Qw);

    gemm_bb3<64, false><<<dim3(16, 32), 256, 0, stream>>>(
        Qw, Wob, Wob, Wob, bo, bo, bo, out, out, out);
}

// Round 9
// 234.346 us; speedup vs baseline: 1.0315x; 1.0315x over previous
//
#include <hip/hip_runtime.h>
#include <hip/hip_bf16.h>

#define SEQ   2048
#define EMB   1024
#define NHEAD 16
#define DHEAD 64
#define BATCH 2
#define MTOT  (BATCH*SEQ)   // 4096
#define QT    128           // queries per attention block
#define KT    64            // keys per tile
#define NTILE (SEQ/KT)      // 32

typedef __attribute__((ext_vector_type(8))) short s8v;   // 8 bf16 (4 VGPRs)
typedef __attribute__((ext_vector_type(4))) short s4v;   // 4 bf16 (8 B)
typedef __attribute__((ext_vector_type(4))) float f4v;   // mfma accum

__device__ __forceinline__ short f2b(float f) {
    union { float fl; unsigned u; } v; v.fl = f;
    unsigned u = v.u;
    u = (u + 0x7fffu + ((u >> 16) & 1u)) >> 16;   // round-to-nearest-even
    return (short)u;
}
// packed fp32x2 -> bf16x2 (v_cvt_pk_bf16_f32); rounded values also feed the
// softmax denominator (consistency => rounding-mode-agnostic).
__device__ __forceinline__ unsigned pk2(float a, float b) {
    union { __hip_bfloat162 h; unsigned u; } c;
    c.h = __float22bfloat162_rn(float2{a, b});
    return c.u;
}

#if __has_builtin(__builtin_amdgcn_exp2f)
__device__ __forceinline__ float exp2_fast(float x) { return __builtin_amdgcn_exp2f(x); }
#else
__device__ __forceinline__ float exp2_fast(float x) { return exp2f(x); }
#endif

// gfx950 cross-lane half-swaps: dst upper part <-> src lower part.
__device__ __forceinline__ void pl32swap(unsigned &a, unsigned &b) {
    asm("v_permlane32_swap_b32 %0, %1" : "+v"(a), "+v"(b));
}
__device__ __forceinline__ void pl16swap(unsigned &a, unsigned &b) {
    asm("v_permlane16_swap_b32 %0, %1" : "+v"(a), "+v"(b));
}

// Raw workgroup barrier: LDS-visibility only (lgkmcnt drain), does NOT drain
// vmcnt — outstanding global prefetch loads stay in flight across it.
__device__ __forceinline__ void bar_lds() {
    asm volatile("s_waitcnt lgkmcnt(0)\n\ts_barrier" ::: "memory");
}

// async global->LDS DMA, 16 B/lane; LDS dest = wave-uniform base + lane*16.
__device__ __forceinline__ void gl_lds16(const short* g, short* l) {
    __builtin_amdgcn_global_load_lds(
        (const __attribute__((address_space(1))) void*)g,
        (__attribute__((address_space(3))) void*)l, 16, 0, 0);
}

// ---- fp32 -> bf16 convert + chunk swizzle ----
// Output rows are 1024 bf16 = 16 aligned 128B groups of 8 16B-chunks.
// Chunk c of row r is stored at slot (c&~7) | ((c&7) ^ (r&7)) so that
// global_load_lds' contiguous DMA lands a bank-uniform LDS image.
__global__ __launch_bounds__(256)
void cvt_swz(const float* __restrict__ s0, const float* __restrict__ s1,
             const float* __restrict__ s2, const float* __restrict__ s3,
             const float* __restrict__ s4,
             short* __restrict__ d0, short* __restrict__ d1,
             short* __restrict__ d2, short* __restrict__ d3,
             short* __restrict__ d4)
{
    const int seg = blockIdx.y;
    const float* s = seg == 0 ? s0 : seg == 1 ? s1 : seg == 2 ? s2 : seg == 3 ? s3 : s4;
    short*       d = seg == 0 ? d0 : seg == 1 ? d1 : seg == 2 ? d2 : seg == 3 ? d3 : d4;
    const int nchunk = (seg == 0 ? MTOT * EMB : EMB * EMB) / 8;   // 16B chunks
    const int stride = gridDim.x * 256;
    for (int i = blockIdx.x * 256 + threadIdx.x; i < nchunk; i += stride) {
        const int row = i >> 7;         // 128 chunks per 1024-col row
        const int c   = i & 127;
        const float4 v0 = *(const float4*)(s + (size_t)i * 8);
        const float4 v1 = *(const float4*)(s + (size_t)i * 8 + 4);
        s8v o;
        o[0] = f2b(v0.x); o[1] = f2b(v0.y); o[2] = f2b(v0.z); o[3] = f2b(v0.w);
        o[4] = f2b(v1.x); o[5] = f2b(v1.y); o[6] = f2b(v1.z); o[7] = f2b(v1.w);
        const int cp = (c & ~7) | ((c & 7) ^ (row & 7));
        *(s8v*)(d + (size_t)row * EMB + cp * 8) = o;
    }
}

// NT GEMM via global_load_lds (m97 structure): C = A*W^T + bias.
// A, W are bf16 with swizzled 16B chunks (see cvt_swz). LDS rows unpadded
// (128 B); frag reads address slot (kk*4+quad)^(l16&7) -> bank-uniform.
// FUSED3: 3 matrices (QKV); mat 2 writes V transposed per-head [b][h][d][s].
// mat 0 (Q) output is prescaled by 0.125*log2(e) so attention uses exp2.
//
// r9 epilogue (FUSED3 only): R8 proved scattered sub-line bf16 stores cause
// RMW write amplification (WRITE 195 MB vs 24 ideal, 96 us). Fix: stage the
// 128x128 bf16 C-tile in LDS (reusing As+Ws after the k-loop's final
// barrier), then store with 8 consecutive lanes writing 8x16B = one FULL
// 128B line per transaction (each thread streams 256B contiguous). Q/K keep
// the R8 operand swap (mapping HW-verified) so the LDS write is a s4v
// row-segment; V keeps the original order (s4v along tokens = row-segment
// of its [d][s] layout). Out-proj (fp32, sector-aligned) keeps R3 path.
template<int NT, bool FUSED3>
__global__ __launch_bounds__(256, 3)
void gemm_bb3(const short* __restrict__ A,
              const short* __restrict__ W0, const short* __restrict__ W1, const short* __restrict__ W2,
              const float* __restrict__ B0, const float* __restrict__ B1, const float* __restrict__ B2,
              void* __restrict__ C0, void* __restrict__ C1, void* __restrict__ C2)
{
    constexpr int JN = NT / 32;
    const int K = EMB, N = EMB;
    const int ntiles = EMB / NT;
    const int mat = blockIdx.x / ntiles;
    const int n0  = (blockIdx.x % ntiles) * NT;
    const int m0  = blockIdx.y * 128;
    const short* W  = (mat == 0) ? W0 : (mat == 1 ? W1 : W2);
    const float* Bi = (mat == 0) ? B0 : (mat == 1 ? B1 : B2);
    void*        C  = (mat == 0) ? C0 : (mat == 1 ? C1 : C2);
    const float qscale = (FUSED3 && mat == 0) ? 0.18033688f : 1.0f;  // 1/8*log2e

    __shared__ __align__(16) short smem[128 * 64 + NT * 64];
    short* const As = smem;
    short* const Ws = smem + 128 * 64;

    const int tid  = threadIdx.x;
    const int lane = tid & 63;
    const int wave = tid >> 6;
    const int quad = lane >> 4;
    const int l16  = lane & 15;
    const int l8   = l16 & 7;
    const int wm   = wave >> 1;
    const int wn   = wave & 1;

    f4v acc[4][JN] = {};

    const int srow = lane >> 3;    // staging row within 8-row group
    const int scol = (lane & 7) * 8;

    const bool swp = FUSED3 && (mat != 2);   // wave-uniform operand swap

    for (int k0 = 0; k0 < K; k0 += 64) {
        // ---- async DMA staging: A rows wave*32.., W rows wave*(NT/4).. ----
        #pragma unroll
        for (int p = 0; p < 4; ++p) {
            const int rbase = wave * 32 + p * 8;
            gl_lds16(A + (size_t)(m0 + rbase + srow) * K + k0 + scol,
                     As + rbase * 64);
        }
        #pragma unroll
        for (int p = 0; p < NT / 32; ++p) {
            const int rbase = wave * (NT / 4) + p * 8;
            gl_lds16(W + (size_t)(n0 + rbase + srow) * K + k0 + scol,
                     Ws + rbase * 64);
        }
        __syncthreads();   // drains the DMA (vmcnt) + barrier

        #pragma unroll
        for (int kk = 0; kk < 2; ++kk) {
            const int slot = ((kk * 4 + quad) ^ l8) * 8;
            s8v af[4], wf[JN];
            #pragma unroll
            for (int i = 0; i < 4; ++i)
                af[i] = *(const s8v*)(As + (wm * 64 + i * 16 + l16) * 64 + slot);
            #pragma unroll
            for (int j = 0; j < JN; ++j)
                wf[j] = *(const s8v*)(Ws + (wn * (NT / 2) + j * 16 + l16) * 64 + slot);
            if (swp) {
                // D[n][token]: col=token(l16), row=n(quad*4+reg)
                #pragma unroll
                for (int i = 0; i < 4; ++i)
                    #pragma unroll
                    for (int j = 0; j < JN; ++j)
                        acc[i][j] = __builtin_amdgcn_mfma_f32_16x16x32_bf16(
                            wf[j], af[i], acc[i][j], 0, 0, 0);
            } else {
                // D[token][n]: col=n(l16), row=token(quad*4+reg)
                #pragma unroll
                for (int i = 0; i < 4; ++i)
                    #pragma unroll
                    for (int j = 0; j < JN; ++j)
                        acc[i][j] = __builtin_amdgcn_mfma_f32_16x16x32_bf16(
                            af[i], wf[j], acc[i][j], 0, 0, 0);
            }
        }
        __syncthreads();   // all waves done reading before next overwrite
    }

    if (!FUSED3) {
        // ---- out-proj epilogue (R3-proven): fp32, 64B sector-aligned ----
        #pragma unroll
        for (int j = 0; j < JN; ++j) {
            const int n = n0 + wn * (NT / 2) + j * 16 + l16;
            const float bv = Bi[n];
            #pragma unroll
            for (int i = 0; i < 4; ++i) {
                const int mb = m0 + wm * 64 + i * 16 + quad * 4;
                #pragma unroll
                for (int rr = 0; rr < 4; ++rr)
                    ((float*)C)[(size_t)(mb + rr) * N + n] = acc[i][j][rr] + bv;
            }
        }
        return;
    }

    // ---- FUSED3 epilogue: LDS-staged, full-line coalesced stores ----
    short* const Cs = smem;   // 128 x 128 bf16, 16B-chunk XOR swizzle per row

    if (mat != 2) {
        // tile layout [token][n]; thread holds n=nl..nl+3 for token tok
        #pragma unroll
        for (int j = 0; j < JN; ++j) {
            const int nl = wn * (NT / 2) + j * 16 + quad * 4;
            const float4 bv = *(const float4*)(Bi + n0 + nl);
            #pragma unroll
            for (int i = 0; i < 4; ++i) {
                const int tok = wm * 64 + i * 16 + l16;
                union { unsigned uu[2]; s4v s; } ov;
                ov.uu[0] = pk2((acc[i][j][0] + bv.x) * qscale,
                               (acc[i][j][1] + bv.y) * qscale);
                ov.uu[1] = pk2((acc[i][j][2] + bv.z) * qscale,
                               (acc[i][j][3] + bv.w) * qscale);
                const int ch = wn * 8 + j * 2 + (quad >> 1);   // 16B chunk
                const int ph = ch ^ (tok & 15);
                *(s4v*)(Cs + tok * 128 + ph * 8 + (quad & 1) * 4) = ov.s;
            }
        }
    } else {
        // tile layout [d][token]; thread holds tokens tl..tl+3 for d
        #pragma unroll
        for (int j = 0; j < JN; ++j) {
            const int dl = wn * (NT / 2) + j * 16 + l16;
            const float bv = Bi[n0 + dl];
            #pragma unroll
            for (int i = 0; i < 4; ++i) {
                const int tl = wm * 64 + i * 16 + quad * 4;
                union { unsigned uu[2]; s4v s; } ov;
                ov.uu[0] = pk2(acc[i][j][0] + bv, acc[i][j][1] + bv);
                ov.uu[1] = pk2(acc[i][j][2] + bv, acc[i][j][3] + bv);
                const int ch = wm * 8 + i * 2 + (quad >> 1);   // 16B chunk
                const int ph = ch ^ (dl & 15);
                *(s4v*)(Cs + dl * 128 + ph * 8 + (quad & 1) * 4) = ov.s;
            }
        }
    }
    bar_lds();

    // 8 consecutive lanes cover one 128B half-row -> full-line transactions;
    // each thread streams 256B contiguous of its rows.
    const int c8  = tid & 7;
    const int rg  = tid >> 3;            // 0..31
    if (mat != 2) {
        #pragma unroll
        for (int p = 0; p < 4; ++p) {
            const int row = p * 32 + rg;                  // token 0..127
            short* dst = (short*)C + (size_t)(m0 + row) * EMB + n0;
            #pragma unroll
            for (int hh = 0; hh < 2; ++hh) {
                const int ch = hh * 8 + c8;
                const int ph = ch ^ (row & 15);
                *(s8v*)(dst + ch * 8) = *(const s8v*)(Cs + row * 128 + ph * 8);
            }
        }
    } else {
        const int bb  = m0 >> 11;
        const int s0g = m0 & 2047;
        #pragma unroll
        for (int p = 0; p < 4; ++p) {
            const int row = p * 32 + rg;                  // d 0..127
            short* dst = (short*)C + ((size_t)(bb * 1024 + n0 + row)) * SEQ + s0g;
            #pragma unroll
            for (int hh = 0; hh < 2; ++hh) {
                const int ch = hh * 8 + c8;
                const int ph = ch ^ (row & 15);
                *(s8v*)(dst + ch * 8) = *(const s8v*)(Cs + row * 128 + ph * 8);
            }
        }
    }
}

// MFMA flash attention v7 (proven best: 49.4 us, R3). QT=128, 512 threads
// (8 waves x 16 q-rows), grid 512 = 2 blocks/CU. K/V staged by
// global_load_lds DMA with pre-swizzled per-lane global source addresses;
// waves 0-3 stage K, 4-7 stage V. P all-to-all via permlane; denominator
// via ones-MFMA; XCD head-affinity swizzle; exp2 with prescaled Q.
__global__ __launch_bounds__(512, 4)
void attn_mfma7(const short* Q, const short* __restrict__ Kg,
                const short* __restrict__ Vt, short* O)
{
    // dispatch i -> XCD i&7 (round-robin). Give each XCD 4 (b,h) combos.
    const int i    = blockIdx.x;          // 512 blocks
    const int xcd  = i & 7;
    const int slot = i >> 3;              // 0..63
    const int combo = xcd * 4 + (slot >> 4);   // (b,h) 0..31
    const int qb = slot & 15;                  // 16 q-blocks per (b,h)
    const int h  = combo & 15;
    const int b  = combo >> 4;
    const int q0 = qb * QT;

    const int tid  = threadIdx.x;
    const int lane = tid & 63;
    const int wave = tid >> 6;            // 0..7
    const int quad = lane >> 4;
    const int l16  = lane & 15;
    const int l8   = l16 & 7;

    __shared__ __align__(16) short Ks[2][64 * 64];   // [key][d]   swizzled image
    __shared__ __align__(16) short Vs[2][64 * 64];   // [d][key]   swizzled image

    // Q B-frags (prescaled by 0.125*log2e): wave handles 16 q-rows
    s8v qf[2];
    #pragma unroll
    for (int kk = 0; kk < 2; ++kk)
        qf[kk] = *(const s8v*)(Q + (size_t)(b * SEQ + q0 + wave * 16 + l16) * EMB
                                 + h * DHEAD + kk * 32 + quad * 8);

    f4v oacc[4] = {};   // [j: d-block] -> O^T[d][q]
    f4v sacc    = {};   // ones-MFMA row sums (col = q, all rows equal)
    s8v onef;
    #pragma unroll
    for (int e = 0; e < 8; ++e) onef[e] = (short)0x3F80;   // bf16 1.0

    // ---- DMA staging setup: lane (r,c) covers row r, physical chunk c ----
    const int r = lane >> 3, c = lane & 7;
    const int sc8 = (c ^ r) * 8;               // pre-swizzled source chunk
    const bool isK = wave < 4;
    const int wrow = (wave & 3) * 16;          // 16 rows per stager wave
    const size_t kbase = (size_t)(b * SEQ) * EMB + h * DHEAD;
    const size_t vbase = (size_t)((b * NHEAD + h) * DHEAD) * SEQ;
    // per-lane global source for tile 0
    const short* gsrc = isK ? Kg + kbase + (size_t)(wrow + r) * EMB + sc8
                            : Vt + vbase + (size_t)(wrow + r) * SEQ + sc8;
    const size_t gstep8 = isK ? (size_t)8 * EMB : (size_t)8 * SEQ;  // +8 rows
    const size_t tstep  = isK ? (size_t)KT * EMB : (size_t)KT;      // +1 tile
    short* const lbase  = (isK ? (short*)Ks : (short*)Vs) + wrow * 64;

    // prologue: issue DMA for tile 0 into buf 0
    gl_lds16(gsrc,          lbase);
    gl_lds16(gsrc + gstep8, lbase + 8 * 64);
    const short* gnext = gsrc + tstep;

    for (int t = 0; t < NTILE; ++t) {
        const int buf = t & 1;
        __syncthreads();   // vmcnt(0)+barrier: tile t landed everywhere;
                           // compute(t-1) done everywhere -> buf^1 is free
        if (t + 1 < NTILE) {
            short* ldst = lbase + (buf ^ 1) * (64 * 64);
            gl_lds16(gnext,          ldst);
            gl_lds16(gnext + gstep8, ldst + 8 * 64);
            gnext += tstep;
        }
        const short* KsB = Ks[buf];
        const short* VsB = Vs[buf];

        // ---- S^T[key][q] = K · Q^T (already in log2 domain) ----
        f4v sc[4] = {};
        #pragma unroll
        for (int kk = 0; kk < 2; ++kk) {
            const int ko = ((kk * 4 + quad) ^ l8) * 8;
            s8v kf[4];
            #pragma unroll
            for (int j = 0; j < 4; ++j)
                kf[j] = *(const s8v*)(KsB + (j * 16 + l16) * 64 + ko);
            #pragma unroll
            for (int j = 0; j < 4; ++j)
                sc[j] = __builtin_amdgcn_mfma_f32_16x16x32_bf16(
                    kf[j], qf[kk], sc[j], 0, 0, 0);
        }

        // ---- p = 2^s, pack to bf16 pairs ----
        unsigned u[4][2];
        #pragma unroll
        for (int j = 0; j < 4; ++j) {
            u[j][0] = pk2(exp2_fast(sc[j][0]), exp2_fast(sc[j][1]));
            u[j][1] = pk2(exp2_fast(sc[j][2]), exp2_fast(sc[j][3]));
        }

        // ---- in-register all-to-all over lane bits 4/5 ----
        #pragma unroll
        for (int r2 = 0; r2 < 2; ++r2) {
            pl32swap(u[0][r2], u[1][r2]);   // stage A: b5' = j&1
            pl32swap(u[2][r2], u[3][r2]);
            pl16swap(u[0][r2], u[1][r2]);   // stage B: b4' = orig b5
            pl16swap(u[2][r2], u[3][r2]);
        }
        union { unsigned uu[4]; s8v s; } pfa, pfb;
        pfa.uu[0] = u[0][0]; pfa.uu[1] = u[0][1]; pfa.uu[2] = u[1][0]; pfa.uu[3] = u[1][1];
        pfb.uu[0] = u[2][0]; pfb.uu[1] = u[2][1]; pfb.uu[2] = u[3][0]; pfb.uu[3] = u[3][1];

        // ---- O^T[d][q] += V^T[d][key] · P^T ; row sums via ones-MFMA ----
        #pragma unroll
        for (int kk = 0; kk < 2; ++kk) {
            const s8v pf = kk ? pfb.s : pfa.s;
            sacc = __builtin_amdgcn_mfma_f32_16x16x32_bf16(onef, pf, sacc, 0, 0, 0);
            const int ko = ((kk * 4 + quad) ^ l8) * 8;
            #pragma unroll
            for (int j = 0; j < 4; ++j) {
                const s8v vf = *(const s8v*)(VsB + (j * 16 + l16) * 64 + ko);
                oacc[j] = __builtin_amdgcn_mfma_f32_16x16x32_bf16(
                    vf, pf, oacc[j], 0, 0, 0);
            }
        }
    }

    // ---- denominator: every row of sacc holds the full sum for col q ----
    const float inv = 1.0f / sacc[0];

    __syncthreads();   // everyone done with K/V LDS; reuse all of Ks as Os
    short* Os = (short*)Ks;   // 128 rows x 64 shorts = 16 KB
    #pragma unroll
    for (int j = 0; j < 4; ++j) {
        union { unsigned uu[2]; s4v s; } ov;
        ov.uu[0] = pk2(oacc[j][0] * inv, oacc[j][1] * inv);
        ov.uu[1] = pk2(oacc[j][2] * inv, oacc[j][3] * inv);
        const int pc = ((j * 2 + (quad >> 1)) ^ l8) * 8 + (quad & 1) * 4;
        *(s4v*)(Os + (wave * 16 + l16) * 64 + pc) = ov.s;
    }
    bar_lds();

    // ---- coalesced store: LDS swizzle cancels the output chunk swizzle ----
    const int row = tid >> 2;            // 0..127
    const int cb  = (tid & 3) * 2;       // two physical chunks per thread
    #pragma unroll
    for (int c4 = 0; c4 < 2; ++c4) {
        const int pcc = cb + c4;
        const s8v tt = *(const s8v*)(Os + row * 64 + pcc * 8);
        *(s8v*)(O + (size_t)(b * SEQ + q0 + row) * EMB + h * DHEAD + pcc * 8) = tt;
    }
}

extern "C" void kernel_launch(void* const* d_in, const int* in_sizes, int n_in,
                              void* d_out, int out_size, void* d_ws, size_t ws_size,
                              hipStream_t stream)
{
    const float* x  = (const float*)d_in[0];
    const float* Wq = (const float*)d_in[1];
    const float* bq = (const float*)d_in[2];
    const float* Wk = (const float*)d_in[3];
    const float* bk = (const float*)d_in[4];
    const float* Wv = (const float*)d_in[5];
    const float* bv = (const float*)d_in[6];
    const float* Wo = (const float*)d_in[7];
    const float* bo = (const float*)d_in[8];
    float* out = (float*)d_out;   // fp32 output

    short* xb  = (short*)d_ws;                       // 4096x1024 bf16, swizzled
    short* Wqb = xb  + (size_t)MTOT * EMB;           // swizzled
    short* Wkb = Wqb + (size_t)EMB * EMB;
    short* Wvb = Wkb + (size_t)EMB * EMB;
    short* Wob = Wvb + (size_t)EMB * EMB;
    short* Qw  = Wob + (size_t)EMB * EMB;            // [token][1024] (Q: plain;
                                                     //  then O: swizzled)
    short* Kw  = Qw  + (size_t)MTOT * EMB;           // [token][1024] plain
    short* Vtw = Kw  + (size_t)MTOT * EMB;           // [b][h][d][s] plain

    cvt_swz<<<dim3(512, 5), 256, 0, stream>>>(x, Wq, Wk, Wv, Wo,
                                              xb, Wqb, Wkb, Wvb, Wob);

    gemm_bb3<128, true><<<dim3(24, 32), 256, 0, stream>>>(
        xb, Wqb, Wkb, Wvb, bq, bk, bv, Qw, Kw, Vtw);

    attn_mfma7<<<dim3(BATCH * NHEAD * (SEQ / QT)), 512, 0, stream>>>(Qw, Kw, Vtw, Qw);

    gemm_bb3<64, false><<<dim3(16, 32), 256, 0, stream>>>(
        Qw, Wob, Wob, Wob, bo, bo, bo, out, out, out);
}

// Round 10
// 180.556 us; speedup vs baseline: 1.3388x; 1.2979x over previous
//
#include <hip/hip_runtime.h>
#include <hip/hip_bf16.h>

#define SEQ   2048
#define EMB   1024
#define NHEAD 16
#define DHEAD 64
#define BATCH 2
#define MTOT  (BATCH*SEQ)   // 4096
#define QT    128           // queries per attention block
#define KT    64            // keys per tile
#define NTILE (SEQ/KT)      // 32

typedef __attribute__((ext_vector_type(8))) short s8v;   // 8 bf16 (4 VGPRs)
typedef __attribute__((ext_vector_type(4))) short s4v;   // 4 bf16 (8 B)
typedef __attribute__((ext_vector_type(4))) float f4v;   // mfma accum

__device__ __forceinline__ short f2b(float f) {
    union { float fl; unsigned u; } v; v.fl = f;
    unsigned u = v.u;
    u = (u + 0x7fffu + ((u >> 16) & 1u)) >> 16;   // round-to-nearest-even
    return (short)u;
}
// packed fp32x2 -> bf16x2 (v_cvt_pk_bf16_f32); rounded values also feed the
// softmax denominator (consistency => rounding-mode-agnostic).
__device__ __forceinline__ unsigned pk2(float a, float b) {
    union { __hip_bfloat162 h; unsigned u; } c;
    c.h = __float22bfloat162_rn(float2{a, b});
    return c.u;
}

#if __has_builtin(__builtin_amdgcn_exp2f)
__device__ __forceinline__ float exp2_fast(float x) { return __builtin_amdgcn_exp2f(x); }
#else
__device__ __forceinline__ float exp2_fast(float x) { return exp2f(x); }
#endif

// gfx950 cross-lane half-swaps: dst upper part <-> src lower part.
__device__ __forceinline__ void pl32swap(unsigned &a, unsigned &b) {
    asm("v_permlane32_swap_b32 %0, %1" : "+v"(a), "+v"(b));
}
__device__ __forceinline__ void pl16swap(unsigned &a, unsigned &b) {
    asm("v_permlane16_swap_b32 %0, %1" : "+v"(a), "+v"(b));
}

// Raw workgroup barrier: LDS-visibility only (lgkmcnt drain), does NOT drain
// vmcnt — outstanding global prefetch loads stay in flight across it.
__device__ __forceinline__ void bar_lds() {
    asm volatile("s_waitcnt lgkmcnt(0)\n\ts_barrier" ::: "memory");
}

// async global->LDS DMA, 16 B/lane; LDS dest = wave-uniform base + lane*16.
__device__ __forceinline__ void gl_lds16(const short* g, short* l) {
    __builtin_amdgcn_global_load_lds(
        (const __attribute__((address_space(1))) void*)g,
        (__attribute__((address_space(3))) void*)l, 16, 0, 0);
}

// ---- fp32 -> bf16 convert + chunk swizzle ----
// Output rows are 1024 bf16 = 16 aligned 128B groups of 8 16B-chunks.
// Chunk c of row r is stored at slot (c&~7) | ((c&7) ^ (r&7)) so that
// global_load_lds' contiguous DMA lands a bank-uniform LDS image.
__global__ __launch_bounds__(256)
void cvt_swz(const float* __restrict__ s0, const float* __restrict__ s1,
             const float* __restrict__ s2, const float* __restrict__ s3,
             const float* __restrict__ s4,
             short* __restrict__ d0, short* __restrict__ d1,
             short* __restrict__ d2, short* __restrict__ d3,
             short* __restrict__ d4)
{
    const int seg = blockIdx.y;
    const float* s = seg == 0 ? s0 : seg == 1 ? s1 : seg == 2 ? s2 : seg == 3 ? s3 : s4;
    short*       d = seg == 0 ? d0 : seg == 1 ? d1 : seg == 2 ? d2 : seg == 3 ? d3 : d4;
    const int nchunk = (seg == 0 ? MTOT * EMB : EMB * EMB) / 8;   // 16B chunks
    const int stride = gridDim.x * 256;
    for (int i = blockIdx.x * 256 + threadIdx.x; i < nchunk; i += stride) {
        const int row = i >> 7;         // 128 chunks per 1024-col row
        const int c   = i & 127;
        const float4 v0 = *(const float4*)(s + (size_t)i * 8);
        const float4 v1 = *(const float4*)(s + (size_t)i * 8 + 4);
        s8v o;
        o[0] = f2b(v0.x); o[1] = f2b(v0.y); o[2] = f2b(v0.z); o[3] = f2b(v0.w);
        o[4] = f2b(v1.x); o[5] = f2b(v1.y); o[6] = f2b(v1.z); o[7] = f2b(v1.w);
        const int cp = (c & ~7) | ((c & 7) ^ (row & 7));
        *(s8v*)(d + (size_t)row * EMB + cp * 8) = o;
    }
}

// NT GEMM via global_load_lds (m97 structure): C = A*W^T + bias.
// A, W are bf16 with swizzled 16B chunks (see cvt_swz). LDS rows unpadded
// (128 B); frag reads address slot (kk*4+quad)^(l16&7) -> bank-uniform.
// FUSED3: 3 matrices (QKV); mat 2 writes V transposed per-head [b][h][d][s].
// mat 0 (Q) output is prescaled by 0.125*log2(e) so attention uses exp2.
//
// r10: EXACT R3 body (R8/R9 epilogue rewrites regressed 53->90+ us with
// unexplained 180 MB WRITE; reverted). NEW: 2D XCD region swizzle.
// HW round-robins linear block id across 8 XCDs (xcd = L%8; s = L/8 is
// sequential per XCD). Linear dispatch gave every XCD all 32 A-tiles
// (FETCH 64 MB of A re-reads, measured 76 MB total on R9). Remap so each
// XCD owns a 2D region (12x*8y for FUSED3, 8x*8y for out-proj), y-fastest:
// resident set = A-group (2 MB) + hot W-tile <= 4 MB L2 -> each tile
// fetched once per region. Predicted FETCH: 76 -> ~40 MB (gemm1),
// ~66 -> ~24 MB (gemm2).
template<int NT, bool FUSED3>
__global__ __launch_bounds__(256, 3)
void gemm_bb3(const short* __restrict__ A,
              const short* __restrict__ W0, const short* __restrict__ W1, const short* __restrict__ W2,
              const float* __restrict__ B0, const float* __restrict__ B1, const float* __restrict__ B2,
              void* __restrict__ C0, void* __restrict__ C1, void* __restrict__ C2)
{
    constexpr int JN = NT / 32;
    const int K = EMB, N = EMB;
    const int ntiles = EMB / NT;

    // ---- 2D XCD region swizzle (bijective remap of the tile grid) ----
    const int L   = blockIdx.x + gridDim.x * blockIdx.y;   // dispatch order
    const int xcd = L & 7;
    const int s   = L >> 3;                                // per-XCD sequence
    constexpr int XW = FUSED3 ? 12 : 8;                    // x-tiles per region
    const int x = (xcd & 1) * XW + s / 8;                  // y-fastest order
    const int y = (xcd >> 1) * 8 + (s & 7);

    const int mat = x / ntiles;
    const int n0  = (x % ntiles) * NT;
    const int m0  = y * 128;
    const short* W  = (mat == 0) ? W0 : (mat == 1 ? W1 : W2);
    const float* Bi = (mat == 0) ? B0 : (mat == 1 ? B1 : B2);
    void*        C  = (mat == 0) ? C0 : (mat == 1 ? C1 : C2);
    const float qscale = (FUSED3 && mat == 0) ? 0.18033688f : 1.0f;  // 1/8*log2e

    __shared__ __align__(16) short As[128 * 64];
    __shared__ __align__(16) short Ws[NT * 64];

    const int tid  = threadIdx.x;
    const int lane = tid & 63;
    const int wave = tid >> 6;
    const int quad = lane >> 4;
    const int l16  = lane & 15;
    const int l8   = l16 & 7;
    const int wm   = wave >> 1;
    const int wn   = wave & 1;

    f4v acc[4][JN] = {};

    const int srow = lane >> 3;    // staging row within 8-row group
    const int scol = (lane & 7) * 8;

    for (int k0 = 0; k0 < K; k0 += 64) {
        // ---- async DMA staging: A rows wave*32.., W rows wave*(NT/4).. ----
        #pragma unroll
        for (int p = 0; p < 4; ++p) {
            const int rbase = wave * 32 + p * 8;
            gl_lds16(A + (size_t)(m0 + rbase + srow) * K + k0 + scol,
                     As + rbase * 64);
        }
        #pragma unroll
        for (int p = 0; p < NT / 32; ++p) {
            const int rbase = wave * (NT / 4) + p * 8;
            gl_lds16(W + (size_t)(n0 + rbase + srow) * K + k0 + scol,
                     Ws + rbase * 64);
        }
        __syncthreads();   // drains the DMA (vmcnt) + barrier

        #pragma unroll
        for (int kk = 0; kk < 2; ++kk) {
            const int slot = ((kk * 4 + quad) ^ l8) * 8;
            s8v af[4], wf[JN];
            #pragma unroll
            for (int i = 0; i < 4; ++i)
                af[i] = *(const s8v*)(As + (wm * 64 + i * 16 + l16) * 64 + slot);
            #pragma unroll
            for (int j = 0; j < JN; ++j)
                wf[j] = *(const s8v*)(Ws + (wn * (NT / 2) + j * 16 + l16) * 64 + slot);
            #pragma unroll
            for (int i = 0; i < 4; ++i)
                #pragma unroll
                for (int j = 0; j < JN; ++j)
                    acc[i][j] = __builtin_amdgcn_mfma_f32_16x16x32_bf16(
                        af[i], wf[j], acc[i][j], 0, 0, 0);
        }
        __syncthreads();   // all waves done reading before next overwrite
    }

    // C/D layout: col = lane&15 (n), row = quad*4+reg (m)   [m89-verified]
    #pragma unroll
    for (int j = 0; j < JN; ++j) {
        const int n = n0 + wn * (NT / 2) + j * 16 + l16;
        const float bv = Bi[n];
        #pragma unroll
        for (int i = 0; i < 4; ++i) {
            const int mb = m0 + wm * 64 + i * 16 + quad * 4;
            if (FUSED3 && mat == 2) {
                const int bb = mb >> 11, ss = mb & 2047;
                s4v ov;
                #pragma unroll
                for (int rr = 0; rr < 4; ++rr) ov[rr] = f2b(acc[i][j][rr] + bv);
                *(s4v*)((short*)C + ((size_t)(bb * 1024 + n)) * SEQ + ss) = ov;
            } else if (FUSED3) {
                #pragma unroll
                for (int rr = 0; rr < 4; ++rr)
                    ((short*)C)[(size_t)(mb + rr) * N + n] = f2b((acc[i][j][rr] + bv) * qscale);
            } else {
                #pragma unroll
                for (int rr = 0; rr < 4; ++rr)
                    ((float*)C)[(size_t)(mb + rr) * N + n] = acc[i][j][rr] + bv;
            }
        }
    }
}

// MFMA flash attention v7 (proven best: 49.4 us, R3). QT=128, 512 threads
// (8 waves x 16 q-rows), grid 512 = 2 blocks/CU. K/V staged by
// global_load_lds DMA with pre-swizzled per-lane global source addresses;
// waves 0-3 stage K, 4-7 stage V. P all-to-all via permlane; denominator
// via ones-MFMA; XCD head-affinity swizzle; exp2 with prescaled Q.
__global__ __launch_bounds__(512, 4)
void attn_mfma7(const short* Q, const short* __restrict__ Kg,
                const short* __restrict__ Vt, short* O)
{
    // dispatch i -> XCD i&7 (round-robin). Give each XCD 4 (b,h) combos.
    const int i    = blockIdx.x;          // 512 blocks
    const int xcd  = i & 7;
    const int slot = i >> 3;              // 0..63
    const int combo = xcd * 4 + (slot >> 4);   // (b,h) 0..31
    const int qb = slot & 15;                  // 16 q-blocks per (b,h)
    const int h  = combo & 15;
    const int b  = combo >> 4;
    const int q0 = qb * QT;

    const int tid  = threadIdx.x;
    const int lane = tid & 63;
    const int wave = tid >> 6;            // 0..7
    const int quad = lane >> 4;
    const int l16  = lane & 15;
    const int l8   = l16 & 7;

    __shared__ __align__(16) short Ks[2][64 * 64];   // [key][d]   swizzled image
    __shared__ __align__(16) short Vs[2][64 * 64];   // [d][key]   swizzled image

    // Q B-frags (prescaled by 0.125*log2e): wave handles 16 q-rows
    s8v qf[2];
    #pragma unroll
    for (int kk = 0; kk < 2; ++kk)
        qf[kk] = *(const s8v*)(Q + (size_t)(b * SEQ + q0 + wave * 16 + l16) * EMB
                                 + h * DHEAD + kk * 32 + quad * 8);

    f4v oacc[4] = {};   // [j: d-block] -> O^T[d][q]
    f4v sacc    = {};   // ones-MFMA row sums (col = q, all rows equal)
    s8v onef;
    #pragma unroll
    for (int e = 0; e < 8; ++e) onef[e] = (short)0x3F80;   // bf16 1.0

    // ---- DMA staging setup: lane (r,c) covers row r, physical chunk c ----
    const int r = lane >> 3, c = lane & 7;
    const int sc8 = (c ^ r) * 8;               // pre-swizzled source chunk
    const bool isK = wave < 4;
    const int wrow = (wave & 3) * 16;          // 16 rows per stager wave
    const size_t kbase = (size_t)(b * SEQ) * EMB + h * DHEAD;
    const size_t vbase = (size_t)((b * NHEAD + h) * DHEAD) * SEQ;
    // per-lane global source for tile 0
    const short* gsrc = isK ? Kg + kbase + (size_t)(wrow + r) * EMB + sc8
                            : Vt + vbase + (size_t)(wrow + r) * SEQ + sc8;
    const size_t gstep8 = isK ? (size_t)8 * EMB : (size_t)8 * SEQ;  // +8 rows
    const size_t tstep  = isK ? (size_t)KT * EMB : (size_t)KT;      // +1 tile
    short* const lbase  = (isK ? (short*)Ks : (short*)Vs) + wrow * 64;

    // prologue: issue DMA for tile 0 into buf 0
    gl_lds16(gsrc,          lbase);
    gl_lds16(gsrc + gstep8, lbase + 8 * 64);
    const short* gnext = gsrc + tstep;

    for (int t = 0; t < NTILE; ++t) {
        const int buf = t & 1;
        __syncthreads();   // vmcnt(0)+barrier: tile t landed everywhere;
                           // compute(t-1) done everywhere -> buf^1 is free
        if (t + 1 < NTILE) {
            short* ldst = lbase + (buf ^ 1) * (64 * 64);
            gl_lds16(gnext,          ldst);
            gl_lds16(gnext + gstep8, ldst + 8 * 64);
            gnext += tstep;
        }
        const short* KsB = Ks[buf];
        const short* VsB = Vs[buf];

        // ---- S^T[key][q] = K · Q^T (already in log2 domain) ----
        f4v sc[4] = {};
        #pragma unroll
        for (int kk = 0; kk < 2; ++kk) {
            const int ko = ((kk * 4 + quad) ^ l8) * 8;
            s8v kf[4];
            #pragma unroll
            for (int j = 0; j < 4; ++j)
                kf[j] = *(const s8v*)(KsB + (j * 16 + l16) * 64 + ko);
            #pragma unroll
            for (int j = 0; j < 4; ++j)
                sc[j] = __builtin_amdgcn_mfma_f32_16x16x32_bf16(
                    kf[j], qf[kk], sc[j], 0, 0, 0);
        }

        // ---- p = 2^s, pack to bf16 pairs ----
        unsigned u[4][2];
        #pragma unroll
        for (int j = 0; j < 4; ++j) {
            u[j][0] = pk2(exp2_fast(sc[j][0]), exp2_fast(sc[j][1]));
            u[j][1] = pk2(exp2_fast(sc[j][2]), exp2_fast(sc[j][3]));
        }

        // ---- in-register all-to-all over lane bits 4/5 ----
        #pragma unroll
        for (int r2 = 0; r2 < 2; ++r2) {
            pl32swap(u[0][r2], u[1][r2]);   // stage A: b5' = j&1
            pl32swap(u[2][r2], u[3][r2]);
            pl16swap(u[0][r2], u[1][r2]);   // stage B: b4' = orig b5
            pl16swap(u[2][r2], u[3][r2]);
        }
        union { unsigned uu[4]; s8v s; } pfa, pfb;
        pfa.uu[0] = u[0][0]; pfa.uu[1] = u[0][1]; pfa.uu[2] = u[1][0]; pfa.uu[3] = u[1][1];
        pfb.uu[0] = u[2][0]; pfb.uu[1] = u[2][1]; pfb.uu[2] = u[3][0]; pfb.uu[3] = u[3][1];

        // ---- O^T[d][q] += V^T[d][key] · P^T ; row sums via ones-MFMA ----
        #pragma unroll
        for (int kk = 0; kk < 2; ++kk) {
            const s8v pf = kk ? pfb.s : pfa.s;
            sacc = __builtin_amdgcn_mfma_f32_16x16x32_bf16(onef, pf, sacc, 0, 0, 0);
            const int ko = ((kk * 4 + quad) ^ l8) * 8;
            #pragma unroll
            for (int j = 0; j < 4; ++j) {
                const s8v vf = *(const s8v*)(VsB + (j * 16 + l16) * 64 + ko);
                oacc[j] = __builtin_amdgcn_mfma_f32_16x16x32_bf16(
                    vf, pf, oacc[j], 0, 0, 0);
            }
        }
    }

    // ---- denominator: every row of sacc holds the full sum for col q ----
    const float inv = 1.0f / sacc[0];

    __syncthreads();   // everyone done with K/V LDS; reuse all of Ks as Os
    short* Os = (short*)Ks;   // 128 rows x 64 shorts = 16 KB
    #pragma unroll
    for (int j = 0; j < 4; ++j) {
        union { unsigned uu[2]; s4v s; } ov;
        ov.uu[0] = pk2(oacc[j][0] * inv, oacc[j][1] * inv);
        ov.uu[1] = pk2(oacc[j][2] * inv, oacc[j][3] * inv);
        const int pc = ((j * 2 + (quad >> 1)) ^ l8) * 8 + (quad & 1) * 4;
        *(s4v*)(Os + (wave * 16 + l16) * 64 + pc) = ov.s;
    }
    bar_lds();

    // ---- coalesced store: LDS swizzle cancels the output chunk swizzle ----
    const int row = tid >> 2;            // 0..127
    const int cb  = (tid & 3) * 2;       // two physical chunks per thread
    #pragma unroll
    for (int c4 = 0; c4 < 2; ++c4) {
        const int pcc = cb + c4;
        const s8v tt = *(const s8v*)(Os + row * 64 + pcc * 8);
        *(s8v*)(O + (size_t)(b * SEQ + q0 + row) * EMB + h * DHEAD + pcc * 8) = tt;
    }
}

extern "C" void kernel_launch(void* const* d_in, const int* in_sizes, int n_in,
                              void* d_out, int out_size, void* d_ws, size_t ws_size,
                              hipStream_t stream)
{
    const float* x  = (const float*)d_in[0];
    const float* Wq = (const float*)d_in[1];
    const float* bq = (const float*)d_in[2];
    const float* Wk = (const float*)d_in[3];
    const float* bk = (const float*)d_in[4];
    const float* Wv = (const float*)d_in[5];
    const float* bv = (const float*)d_in[6];
    const float* Wo = (const float*)d_in[7];
    const float* bo = (const float*)d_in[8];
    float* out = (float*)d_out;   // fp32 output

    short* xb  = (short*)d_ws;                       // 4096x1024 bf16, swizzled
    short* Wqb = xb  + (size_t)MTOT * EMB;           // swizzled
    short* Wkb = Wqb + (size_t)EMB * EMB;
    short* Wvb = Wkb + (size_t)EMB * EMB;
    short* Wob = Wvb + (size_t)EMB * EMB;
    short* Qw  = Wob + (size_t)EMB * EMB;            // [token][1024] (Q: plain;
                                                     //  then O: swizzled)
    short* Kw  = Qw  + (size_t)MTOT * EMB;           // [token][1024] plain
    short* Vtw = Kw  + (size_t)MTOT * EMB;           // [b][h][d][s] plain

    cvt_swz<<<dim3(512, 5), 256, 0, stream>>>(x, Wq, Wk, Wv, Wo,
                                              xb, Wqb, Wkb, Wvb, Wob);

    gemm_bb3<128, true><<<dim3(24, 32), 256, 0, stream>>>(
        xb, Wqb, Wkb, Wvb, bq, bk, bv, Qw, Kw, Vtw);

    attn_mfma7<<<dim3(BATCH * NHEAD * (SEQ / QT)), 512, 0, stream>>>(Qw, Kw, Vtw, Qw);

    gemm_bb3<64, false><<<dim3(16, 32), 256, 0, stream>>>(
        Qw, Wob, Wob, Wob, bo, bo, bo, out, out, out);
}

// Round 11
// 177.722 us; speedup vs baseline: 1.3602x; 1.0159x over previous
//
#include <hip/hip_runtime.h>
#include <hip/hip_bf16.h>

#define SEQ   2048
#define EMB   1024
#define NHEAD 16
#define DHEAD 64
#define BATCH 2
#define MTOT  (BATCH*SEQ)   // 4096
#define QT    128           // queries per attention block
#define KT    64            // keys per tile
#define NTILE (SEQ/KT)      // 32

typedef __attribute__((ext_vector_type(8))) short s8v;   // 8 bf16 (4 VGPRs)
typedef __attribute__((ext_vector_type(4))) short s4v;   // 4 bf16 (8 B)
typedef __attribute__((ext_vector_type(4))) float f4v;   // mfma accum

__device__ __forceinline__ short f2b(float f) {
    union { float fl; unsigned u; } v; v.fl = f;
    unsigned u = v.u;
    u = (u + 0x7fffu + ((u >> 16) & 1u)) >> 16;   // round-to-nearest-even
    return (short)u;
}
// packed fp32x2 -> bf16x2 (v_cvt_pk_bf16_f32); rounded values also feed the
// softmax denominator (consistency => rounding-mode-agnostic).
__device__ __forceinline__ unsigned pk2(float a, float b) {
    union { __hip_bfloat162 h; unsigned u; } c;
    c.h = __float22bfloat162_rn(float2{a, b});
    return c.u;
}

#if __has_builtin(__builtin_amdgcn_exp2f)
__device__ __forceinline__ float exp2_fast(float x) { return __builtin_amdgcn_exp2f(x); }
#else
__device__ __forceinline__ float exp2_fast(float x) { return exp2f(x); }
#endif

// gfx950 cross-lane half-swaps: dst upper part <-> src lower part.
__device__ __forceinline__ void pl32swap(unsigned &a, unsigned &b) {
    asm("v_permlane32_swap_b32 %0, %1" : "+v"(a), "+v"(b));
}
__device__ __forceinline__ void pl16swap(unsigned &a, unsigned &b) {
    asm("v_permlane16_swap_b32 %0, %1" : "+v"(a), "+v"(b));
}

// Raw workgroup barrier: LDS-visibility only (lgkmcnt drain), does NOT drain
// vmcnt — outstanding global prefetch loads stay in flight across it.
__device__ __forceinline__ void bar_lds() {
    asm volatile("s_waitcnt lgkmcnt(0)\n\ts_barrier" ::: "memory");
}

// async global->LDS DMA, 16 B/lane; LDS dest = wave-uniform base + lane*16.
__device__ __forceinline__ void gl_lds16(const short* g, short* l) {
    __builtin_amdgcn_global_load_lds(
        (const __attribute__((address_space(1))) void*)g,
        (__attribute__((address_space(3))) void*)l, 16, 0, 0);
}

// ---- fp32 -> bf16 convert + chunk swizzle ----
// Output rows are 1024 bf16 = 16 aligned 128B groups of 8 16B-chunks.
// Chunk c of row r is stored at slot (c&~7) | ((c&7) ^ (r&7)) so that
// global_load_lds' contiguous DMA lands a bank-uniform LDS image.
// r11: rounding via v_cvt_pk_bf16_f32 (bit-identical RNE to f2b, half the VALU).
__global__ __launch_bounds__(256)
void cvt_swz(const float* __restrict__ s0, const float* __restrict__ s1,
             const float* __restrict__ s2, const float* __restrict__ s3,
             const float* __restrict__ s4,
             short* __restrict__ d0, short* __restrict__ d1,
             short* __restrict__ d2, short* __restrict__ d3,
             short* __restrict__ d4)
{
    const int seg = blockIdx.y;
    const float* s = seg == 0 ? s0 : seg == 1 ? s1 : seg == 2 ? s2 : seg == 3 ? s3 : s4;
    short*       d = seg == 0 ? d0 : seg == 1 ? d1 : seg == 2 ? d2 : seg == 3 ? d3 : d4;
    const int nchunk = (seg == 0 ? MTOT * EMB : EMB * EMB) / 8;   // 16B chunks
    const int stride = gridDim.x * 256;
    for (int i = blockIdx.x * 256 + threadIdx.x; i < nchunk; i += stride) {
        const int row = i >> 7;         // 128 chunks per 1024-col row
        const int c   = i & 127;
        const float4 v0 = *(const float4*)(s + (size_t)i * 8);
        const float4 v1 = *(const float4*)(s + (size_t)i * 8 + 4);
        union { unsigned uu[4]; s8v s8; } o;
        o.uu[0] = pk2(v0.x, v0.y);
        o.uu[1] = pk2(v0.z, v0.w);
        o.uu[2] = pk2(v1.x, v1.y);
        o.uu[3] = pk2(v1.z, v1.w);
        const int cp = (c & ~7) | ((c & 7) ^ (row & 7));
        *(s8v*)(d + (size_t)row * EMB + cp * 8) = o.s8;
    }
}

// NT GEMM via global_load_lds (m97 structure): C = A*W^T + bias.
// A, W are bf16 with swizzled 16B chunks (see cvt_swz). LDS rows unpadded
// (128 B); frag reads address slot (kk*4+quad)^(l16&7) -> bank-uniform.
// FUSED3: 3 matrices (QKV); mat 2 writes V transposed per-head [b][h][d][s].
// mat 0 (Q) output is prescaled by 0.125*log2(e) so attention uses exp2.
// 2D XCD region swizzle (r10): each XCD owns a contiguous 2D tile region.
//
// r11: the out-projection instantiation (FUSED3=false) gets the attn_mfma7
// loop structure — DOUBLE-buffered LDS + ONE __syncthreads per K-step (DMA
// for tile t+1 issued after the barrier, in flight across compute(t)).
// Halves the barrier-drain count 32 -> 16. LDS 24 -> 48 KB, still >= the
// 2 blocks/CU this 512-block grid needs. gemm1 (FUSED3) keeps the 2-barrier
// single-buffer body: its dbuf would need 64 KB -> 2 blocks/CU and its
// 768-block grid would serialize into 1.5 rounds (net loss).
template<int NT, bool FUSED3>
__global__ __launch_bounds__(256, 3)
void gemm_bb3(const short* __restrict__ A,
              const short* __restrict__ W0, const short* __restrict__ W1, const short* __restrict__ W2,
              const float* __restrict__ B0, const float* __restrict__ B1, const float* __restrict__ B2,
              void* __restrict__ C0, void* __restrict__ C1, void* __restrict__ C2)
{
    constexpr int JN = NT / 32;
    const int K = EMB, N = EMB;
    const int ntiles = EMB / NT;

    // ---- 2D XCD region swizzle (bijective remap of the tile grid) ----
    const int L   = blockIdx.x + gridDim.x * blockIdx.y;   // dispatch order
    const int xcd = L & 7;
    const int s   = L >> 3;                                // per-XCD sequence
    constexpr int XW = FUSED3 ? 12 : 8;                    // x-tiles per region
    const int x = (xcd & 1) * XW + s / 8;                  // y-fastest order
    const int y = (xcd >> 1) * 8 + (s & 7);

    const int mat = x / ntiles;
    const int n0  = (x % ntiles) * NT;
    const int m0  = y * 128;
    const short* W  = (mat == 0) ? W0 : (mat == 1 ? W1 : W2);
    const float* Bi = (mat == 0) ? B0 : (mat == 1 ? B1 : B2);
    void*        C  = (mat == 0) ? C0 : (mat == 1 ? C1 : C2);
    const float qscale = (FUSED3 && mat == 0) ? 0.18033688f : 1.0f;  // 1/8*log2e

    const int tid  = threadIdx.x;
    const int lane = tid & 63;
    const int wave = tid >> 6;
    const int quad = lane >> 4;
    const int l16  = lane & 15;
    const int l8   = l16 & 7;
    const int wm   = wave >> 1;
    const int wn   = wave & 1;

    f4v acc[4][JN] = {};

    const int srow = lane >> 3;    // staging row within 8-row group
    const int scol = (lane & 7) * 8;

    if constexpr (FUSED3) {
        // ---- 2-barrier single-buffer body (R3-proven) ----
        __shared__ __align__(16) short As[128 * 64];
        __shared__ __align__(16) short Ws[NT * 64];

        for (int k0 = 0; k0 < K; k0 += 64) {
            #pragma unroll
            for (int p = 0; p < 4; ++p) {
                const int rbase = wave * 32 + p * 8;
                gl_lds16(A + (size_t)(m0 + rbase + srow) * K + k0 + scol,
                         As + rbase * 64);
            }
            #pragma unroll
            for (int p = 0; p < NT / 32; ++p) {
                const int rbase = wave * (NT / 4) + p * 8;
                gl_lds16(W + (size_t)(n0 + rbase + srow) * K + k0 + scol,
                         Ws + rbase * 64);
            }
            __syncthreads();   // drains the DMA (vmcnt) + barrier

            #pragma unroll
            for (int kk = 0; kk < 2; ++kk) {
                const int slot = ((kk * 4 + quad) ^ l8) * 8;
                s8v af[4], wf[JN];
                #pragma unroll
                for (int i = 0; i < 4; ++i)
                    af[i] = *(const s8v*)(As + (wm * 64 + i * 16 + l16) * 64 + slot);
                #pragma unroll
                for (int j = 0; j < JN; ++j)
                    wf[j] = *(const s8v*)(Ws + (wn * (NT / 2) + j * 16 + l16) * 64 + slot);
                #pragma unroll
                for (int i = 0; i < 4; ++i)
                    #pragma unroll
                    for (int j = 0; j < JN; ++j)
                        acc[i][j] = __builtin_amdgcn_mfma_f32_16x16x32_bf16(
                            af[i], wf[j], acc[i][j], 0, 0, 0);
            }
            __syncthreads();   // all waves done reading before next overwrite
        }

        // C/D layout: col = lane&15 (n), row = quad*4+reg (m)  [m89-verified]
        #pragma unroll
        for (int j = 0; j < JN; ++j) {
            const int n = n0 + wn * (NT / 2) + j * 16 + l16;
            const float bv = Bi[n];
            #pragma unroll
            for (int i = 0; i < 4; ++i) {
                const int mb = m0 + wm * 64 + i * 16 + quad * 4;
                if (mat == 2) {
                    const int bb = mb >> 11, ss = mb & 2047;
                    s4v ov;
                    #pragma unroll
                    for (int rr = 0; rr < 4; ++rr) ov[rr] = f2b(acc[i][j][rr] + bv);
                    *(s4v*)((short*)C + ((size_t)(bb * 1024 + n)) * SEQ + ss) = ov;
                } else {
                    #pragma unroll
                    for (int rr = 0; rr < 4; ++rr)
                        ((short*)C)[(size_t)(mb + rr) * N + n] = f2b((acc[i][j][rr] + bv) * qscale);
                }
            }
        }
    } else {
        // ---- r11: dbuf + 1-barrier body (attn_mfma7 structure) ----
        __shared__ __align__(16) short As[2][128 * 64];
        __shared__ __align__(16) short Ws[2][NT * 64];

        // prologue: issue DMA for K-step 0 into buf 0
        #pragma unroll
        for (int p = 0; p < 4; ++p) {
            const int rbase = wave * 32 + p * 8;
            gl_lds16(A + (size_t)(m0 + rbase + srow) * K + scol, As[0] + rbase * 64);
        }
        #pragma unroll
        for (int p = 0; p < NT / 32; ++p) {
            const int rbase = wave * (NT / 4) + p * 8;
            gl_lds16(W + (size_t)(n0 + rbase + srow) * K + scol, Ws[0] + rbase * 64);
        }

        for (int t = 0; t < K / 64; ++t) {
            const int buf = t & 1;
            __syncthreads();   // vmcnt(0)+barrier: tile t landed everywhere;
                               // compute(t-1) done everywhere -> buf^1 free
            if (t + 1 < K / 64) {
                const int k1 = (t + 1) * 64;
                #pragma unroll
                for (int p = 0; p < 4; ++p) {
                    const int rbase = wave * 32 + p * 8;
                    gl_lds16(A + (size_t)(m0 + rbase + srow) * K + k1 + scol,
                             As[buf ^ 1] + rbase * 64);
                }
                #pragma unroll
                for (int p = 0; p < NT / 32; ++p) {
                    const int rbase = wave * (NT / 4) + p * 8;
                    gl_lds16(W + (size_t)(n0 + rbase + srow) * K + k1 + scol,
                             Ws[buf ^ 1] + rbase * 64);
                }
            }
            const short* AsB = As[buf];
            const short* WsB = Ws[buf];

            #pragma unroll
            for (int kk = 0; kk < 2; ++kk) {
                const int slot = ((kk * 4 + quad) ^ l8) * 8;
                s8v af[4], wf[JN];
                #pragma unroll
                for (int i = 0; i < 4; ++i)
                    af[i] = *(const s8v*)(AsB + (wm * 64 + i * 16 + l16) * 64 + slot);
                #pragma unroll
                for (int j = 0; j < JN; ++j)
                    wf[j] = *(const s8v*)(WsB + (wn * (NT / 2) + j * 16 + l16) * 64 + slot);
                #pragma unroll
                for (int i = 0; i < 4; ++i)
                    #pragma unroll
                    for (int j = 0; j < JN; ++j)
                        acc[i][j] = __builtin_amdgcn_mfma_f32_16x16x32_bf16(
                            af[i], wf[j], acc[i][j], 0, 0, 0);
            }
        }

        // ---- out-proj epilogue (R3-proven): fp32, sector-aligned ----
        #pragma unroll
        for (int j = 0; j < JN; ++j) {
            const int n = n0 + wn * (NT / 2) + j * 16 + l16;
            const float bv = Bi[n];
            #pragma unroll
            for (int i = 0; i < 4; ++i) {
                const int mb = m0 + wm * 64 + i * 16 + quad * 4;
                #pragma unroll
                for (int rr = 0; rr < 4; ++rr)
                    ((float*)C)[(size_t)(mb + rr) * N + n] = acc[i][j][rr] + bv;
            }
        }
    }
}

// MFMA flash attention v7 (proven best: 49.0 us). QT=128, 512 threads
// (8 waves x 16 q-rows), grid 512 = 2 blocks/CU. K/V staged by
// global_load_lds DMA with pre-swizzled per-lane global source addresses;
// waves 0-3 stage K, 4-7 stage V. P all-to-all via permlane; denominator
// via ones-MFMA; XCD head-affinity swizzle; exp2 with prescaled Q.
__global__ __launch_bounds__(512, 4)
void attn_mfma7(const short* Q, const short* __restrict__ Kg,
                const short* __restrict__ Vt, short* O)
{
    // dispatch i -> XCD i&7 (round-robin). Give each XCD 4 (b,h) combos.
    const int i    = blockIdx.x;          // 512 blocks
    const int xcd  = i & 7;
    const int slot = i >> 3;              // 0..63
    const int combo = xcd * 4 + (slot >> 4);   // (b,h) 0..31
    const int qb = slot & 15;                  // 16 q-blocks per (b,h)
    const int h  = combo & 15;
    const int b  = combo >> 4;
    const int q0 = qb * QT;

    const int tid  = threadIdx.x;
    const int lane = tid & 63;
    const int wave = tid >> 6;            // 0..7
    const int quad = lane >> 4;
    const int l16  = lane & 15;
    const int l8   = l16 & 7;

    __shared__ __align__(16) short Ks[2][64 * 64];   // [key][d]   swizzled image
    __shared__ __align__(16) short Vs[2][64 * 64];   // [d][key]   swizzled image

    // Q B-frags (prescaled by 0.125*log2e): wave handles 16 q-rows
    s8v qf[2];
    #pragma unroll
    for (int kk = 0; kk < 2; ++kk)
        qf[kk] = *(const s8v*)(Q + (size_t)(b * SEQ + q0 + wave * 16 + l16) * EMB
                                 + h * DHEAD + kk * 32 + quad * 8);

    f4v oacc[4] = {};   // [j: d-block] -> O^T[d][q]
    f4v sacc    = {};   // ones-MFMA row sums (col = q, all rows equal)
    s8v onef;
    #pragma unroll
    for (int e = 0; e < 8; ++e) onef[e] = (short)0x3F80;   // bf16 1.0

    // ---- DMA staging setup: lane (r,c) covers row r, physical chunk c ----
    const int r = lane >> 3, c = lane & 7;
    const int sc8 = (c ^ r) * 8;               // pre-swizzled source chunk
    const bool isK = wave < 4;
    const int wrow = (wave & 3) * 16;          // 16 rows per stager wave
    const size_t kbase = (size_t)(b * SEQ) * EMB + h * DHEAD;
    const size_t vbase = (size_t)((b * NHEAD + h) * DHEAD) * SEQ;
    // per-lane global source for tile 0
    const short* gsrc = isK ? Kg + kbase + (size_t)(wrow + r) * EMB + sc8
                            : Vt + vbase + (size_t)(wrow + r) * SEQ + sc8;
    const size_t gstep8 = isK ? (size_t)8 * EMB : (size_t)8 * SEQ;  // +8 rows
    const size_t tstep  = isK ? (size_t)KT * EMB : (size_t)KT;      // +1 tile
    short* const lbase  = (isK ? (short*)Ks : (short*)Vs) + wrow * 64;

    // prologue: issue DMA for tile 0 into buf 0
    gl_lds16(gsrc,          lbase);
    gl_lds16(gsrc + gstep8, lbase + 8 * 64);
    const short* gnext = gsrc + tstep;

    for (int t = 0; t < NTILE; ++t) {
        const int buf = t & 1;
        __syncthreads();   // vmcnt(0)+barrier: tile t landed everywhere;
                           // compute(t-1) done everywhere -> buf^1 is free
        if (t + 1 < NTILE) {
            short* ldst = lbase + (buf ^ 1) * (64 * 64);
            gl_lds16(gnext,          ldst);
            gl_lds16(gnext + gstep8, ldst + 8 * 64);
            gnext += tstep;
        }
        const short* KsB = Ks[buf];
        const short* VsB = Vs[buf];

        // ---- S^T[key][q] = K · Q^T (already in log2 domain) ----
        f4v sc[4] = {};
        #pragma unroll
        for (int kk = 0; kk < 2; ++kk) {
            const int ko = ((kk * 4 + quad) ^ l8) * 8;
            s8v kf[4];
            #pragma unroll
            for (int j = 0; j < 4; ++j)
                kf[j] = *(const s8v*)(KsB + (j * 16 + l16) * 64 + ko);
            #pragma unroll
            for (int j = 0; j < 4; ++j)
                sc[j] = __builtin_amdgcn_mfma_f32_16x16x32_bf16(
                    kf[j], qf[kk], sc[j], 0, 0, 0);
        }

        // ---- p = 2^s, pack to bf16 pairs ----
        unsigned u[4][2];
        #pragma unroll
        for (int j = 0; j < 4; ++j) {
            u[j][0] = pk2(exp2_fast(sc[j][0]), exp2_fast(sc[j][1]));
            u[j][1] = pk2(exp2_fast(sc[j][2]), exp2_fast(sc[j][3]));
        }

        // ---- in-register all-to-all over lane bits 4/5 ----
        #pragma unroll
        for (int r2 = 0; r2 < 2; ++r2) {
            pl32swap(u[0][r2], u[1][r2]);   // stage A: b5' = j&1
            pl32swap(u[2][r2], u[3][r2]);
            pl16swap(u[0][r2], u[1][r2]);   // stage B: b4' = orig b5
            pl16swap(u[2][r2], u[3][r2]);
        }
        union { unsigned uu[4]; s8v s; } pfa, pfb;
        pfa.uu[0] = u[0][0]; pfa.uu[1] = u[0][1]; pfa.uu[2] = u[1][0]; pfa.uu[3] = u[1][1];
        pfb.uu[0] = u[2][0]; pfb.uu[1] = u[2][1]; pfb.uu[2] = u[3][0]; pfb.uu[3] = u[3][1];

        // ---- O^T[d][q] += V^T[d][key] · P^T ; row sums via ones-MFMA ----
        #pragma unroll
        for (int kk = 0; kk < 2; ++kk) {
            const s8v pf = kk ? pfb.s : pfa.s;
            sacc = __builtin_amdgcn_mfma_f32_16x16x32_bf16(onef, pf, sacc, 0, 0, 0);
            const int ko = ((kk * 4 + quad) ^ l8) * 8;
            #pragma unroll
            for (int j = 0; j < 4; ++j) {
                const s8v vf = *(const s8v*)(VsB + (j * 16 + l16) * 64 + ko);
                oacc[j] = __builtin_amdgcn_mfma_f32_16x16x32_bf16(
                    vf, pf, oacc[j], 0, 0, 0);
            }
        }
    }

    // ---- denominator: every row of sacc holds the full sum for col q ----
    const float inv = 1.0f / sacc[0];

    __syncthreads();   // everyone done with K/V LDS; reuse all of Ks as Os
    short* Os = (short*)Ks;   // 128 rows x 64 shorts = 16 KB
    #pragma unroll
    for (int j = 0; j < 4; ++j) {
        union { unsigned uu[2]; s4v s; } ov;
        ov.uu[0] = pk2(oacc[j][0] * inv, oacc[j][1] * inv);
        ov.uu[1] = pk2(oacc[j][2] * inv, oacc[j][3] * inv);
        const int pc = ((j * 2 + (quad >> 1)) ^ l8) * 8 + (quad & 1) * 4;
        *(s4v*)(Os + (wave * 16 + l16) * 64 + pc) = ov.s;
    }
    bar_lds();

    // ---- coalesced store: LDS swizzle cancels the output chunk swizzle ----
    const int row = tid >> 2;            // 0..127
    const int cb  = (tid & 3) * 2;       // two physical chunks per thread
    #pragma unroll
    for (int c4 = 0; c4 < 2; ++c4) {
        const int pcc = cb + c4;
        const s8v tt = *(const s8v*)(Os + row * 64 + pcc * 8);
        *(s8v*)(O + (size_t)(b * SEQ + q0 + row) * EMB + h * DHEAD + pcc * 8) = tt;
    }
}

extern "C" void kernel_launch(void* const* d_in, const int* in_sizes, int n_in,
                              void* d_out, int out_size, void* d_ws, size_t ws_size,
                              hipStream_t stream)
{
    const float* x  = (const float*)d_in[0];
    const float* Wq = (const float*)d_in[1];
    const float* bq = (const float*)d_in[2];
    const float* Wk = (const float*)d_in[3];
    const float* bk = (const float*)d_in[4];
    const float* Wv = (const float*)d_in[5];
    const float* bv = (const float*)d_in[6];
    const float* Wo = (const float*)d_in[7];
    const float* bo = (const float*)d_in[8];
    float* out = (float*)d_out;   // fp32 output

    short* xb  = (short*)d_ws;                       // 4096x1024 bf16, swizzled
    short* Wqb = xb  + (size_t)MTOT * EMB;           // swizzled
    short* Wkb = Wqb + (size_t)EMB * EMB;
    short* Wvb = Wkb + (size_t)EMB * EMB;
    short* Wob = Wvb + (size_t)EMB * EMB;
    short* Qw  = Wob + (size_t)EMB * EMB;            // [token][1024] (Q: plain;
                                                     //  then O: swizzled)
    short* Kw  = Qw  + (size_t)MTOT * EMB;           // [token][1024] plain
    short* Vtw = Kw  + (size_t)MTOT * EMB;           // [b][h][d][s] plain

    cvt_swz<<<dim3(512, 5), 256, 0, stream>>>(x, Wq, Wk, Wv, Wo,
                                              xb, Wqb, Wkb, Wvb, Wob);

    gemm_bb3<128, true><<<dim3(24, 32), 256, 0, stream>>>(
        xb, Wqb, Wkb, Wvb, bq, bk, bv, Qw, Kw, Vtw);

    attn_mfma7<<<dim3(BATCH * NHEAD * (SEQ / QT)), 512, 0, stream>>>(Qw, Kw, Vtw, Qw);

    gemm_bb3<64, false><<<dim3(16, 32), 256, 0, stream>>>(
        Qw, Wob, Wob, Wob, bo, bo, bo, out, out, out);
}